// Round 16
// baseline (44.813 us; speedup 1.0000x reference)
//
#include <hip/hip_runtime.h>

#define N     4096
#define ON    4090
#define LDS_P 72         // stripe-window pitch (floats; 288 B, 16B-aligned rows)
#define WB    1024       // floats per buffer = 4 KB = 4 DMA instrs
#define VS    8          // stripes per wave (walks 64 rows)
#define GXW   64         // x wave-tiles, 64 wide
#define GYW   64         // y bands, 64 rows
#define NB    (GXW * GYW / 4)   // 1024 blocks

__device__ __forceinline__ void gload_lds16(const float* g, float* l) {
    __builtin_amdgcn_global_load_lds(
        (const __attribute__((address_space(1))) void*)g,
        (__attribute__((address_space(3))) void*)l,
        16, 0, 0);   // 16 B/lane, dest = uniform base + lane*16
}

// Per-wave double-buffered streaming conv, occupancy-preserving:
// wave owns a 64-col segment, walks 8 stripes of 8 rows; stage(s+1) is in
// flight (counted vmcnt(4), never 0 mid-loop) while computing stripe s.
// No barriers; 32 KB LDS/block -> 4 blocks/CU -> 16 pipelined waves/CU.
// Linear dispatch: consecutive waves x-adjacent -> coherent write front.
__global__ __launch_bounds__(256, 4)
void conv7x7_pipe(const float* __restrict__ x,
                  const float* __restrict__ w,
                  const float* __restrict__ bias,
                  float* __restrict__ out)
{
    __shared__ float lds[4 * 2 * WB];   // 32 KB

    const int tid  = threadIdx.x;
    const int lane = tid & 63;
    const int wv   = tid >> 6;
    float* buf0 = lds + (wv << 11);     // wave-private 2 x 1024 floats

    const int t   = (blockIdx.x << 2) + wv;  // wave-tile id, row-major
    const int bx  = t & (GXW - 1);
    const int by  = t >> 6;
    const int x0  = bx << 6;            // 64-col segment
    const int yb  = by << 6;            // 64-row band base
    const int xc0 = x0 >> 2;

    // weights/bias: uniform addresses -> scalar loads
    float ws[49];
    #pragma unroll
    for (int i = 0; i < 49; ++i) ws[i] = w[i];
    const float bv = bias[0];

    // stage one 14(+ovr)x72 window: 4 width-16 DMAs, flat chunk m->(m/18,m%18)
    auto stage = [&](float* buf, int y0s) {
        #pragma unroll
        for (int k = 0; k < 4; ++k) {
            const int m   = (k << 6) + lane;
            const int row = m / 18;                     // magic-mul
            const int cc  = m - row * 18;
            const int gy  = min(y0s + row, N - 1);      // edge clamps: junk
            const int gc  = min(xc0 + cc, (N >> 2) - 1);// feeds guarded outputs
            gload_lds16(x + ((size_t)gy << 12) + ((size_t)gc << 2),
                        buf + (k << 8));
        }
    };

    stage(buf0, yb);   // prologue: stripe 0

    const int tau   = lane & 15;        // col chunk (4 floats)
    const int rg    = lane >> 4;        // 0..3 -> rows 2rg, 2rg+1
    const int colf  = tau << 2;
    const int rbase = rg << 1;
    const int ox    = x0 + colf;
    const bool inx  = (ox + 4 <= ON);

    #pragma unroll 1
    for (int s = 0; s < VS; ++s) {
        if (s + 1 < VS) {
            stage(buf0 + (((s + 1) & 1) << 10), yb + ((s + 1) << 3));
            asm volatile("s_waitcnt vmcnt(4)" ::: "memory");  // s's loads done,
        } else {                                              // s+1's in flight
            asm volatile("s_waitcnt vmcnt(0)" ::: "memory");
        }
        __builtin_amdgcn_sched_barrier(0);   // no ds_read hoists above the wait

        const float* cbuf = buf0 + ((s & 1) << 10);
        const int y0s = yb + (s << 3);

        float acc[2][4] = {};
        #pragma unroll
        for (int rr = 0; rr < 8; ++rr) {     // 8 window rows feed 2 out rows
            const float* rp = cbuf + (rbase + rr) * LDS_P + colf;
            float v[10];
            const float4 a  = *reinterpret_cast<const float4*>(rp);
            const float4 bq = *reinterpret_cast<const float4*>(rp + 4);
            const float2 c  = *reinterpret_cast<const float2*>(rp + 8);
            v[0]=a.x;  v[1]=a.y;  v[2]=a.z;  v[3]=a.w;
            v[4]=bq.x; v[5]=bq.y; v[6]=bq.z; v[7]=bq.w;
            v[8]=c.x;  v[9]=c.y;

            #pragma unroll
            for (int r = 0; r < 2; ++r) {
                const int ky = rr - r;               // compile-time after unroll
                if (ky >= 0 && ky < 7) {
                    #pragma unroll
                    for (int kx = 0; kx < 7; ++kx) {
                        const float wk = ws[ky * 7 + kx];
                        #pragma unroll
                        for (int j = 0; j < 4; ++j)
                            acc[r][j] = fmaf(v[kx + j], wk, acc[r][j]);
                    }
                }
            }
        }

        const int oy0 = y0s + rbase;
        if (inx && oy0 + 2 <= ON) {
            #pragma unroll
            for (int r = 0; r < 2; ++r) {
                float* dst = out + (size_t)(oy0 + r) * ON + ox;   // 8B-aligned
                *reinterpret_cast<float2*>(dst)     = make_float2(acc[r][0] + bv, acc[r][1] + bv);
                *reinterpret_cast<float2*>(dst + 2) = make_float2(acc[r][2] + bv, acc[r][3] + bv);
            }
        } else {
            #pragma unroll
            for (int r = 0; r < 2; ++r) {
                const int oy = oy0 + r;
                if (oy < ON) {
                    float* dst = out + (size_t)oy * ON;
                    #pragma unroll
                    for (int j = 0; j < 4; ++j) {
                        const int oxj = ox + j;
                        if (oxj < ON) dst[oxj] = acc[r][j] + bv;
                    }
                }
            }
        }
    }
}

extern "C" void kernel_launch(void* const* d_in, const int* in_sizes, int n_in,
                              void* d_out, int out_size, void* d_ws, size_t ws_size,
                              hipStream_t stream) {
    const float* x    = (const float*)d_in[0];
    const float* w    = (const float*)d_in[1];
    const float* bias = (const float*)d_in[2];
    float* out        = (float*)d_out;

    conv7x7_pipe<<<dim3(NB, 1, 1), dim3(256, 1, 1), 0, stream>>>(x, w, bias, out);
}

// Round 17
// 43.619 us; speedup vs baseline: 1.0274x; 1.0274x over previous
//
#include <hip/hip_runtime.h>

#define N     4096
#define ON    4090
#define WROWS 38               // staged rows (32 out + 6 halo)
#define PITCH 256              // LDS row pitch BYTES (power-of-2 region for XOR swizzle)
#define WLDS  (WROWS * PITCH)  // 9728 B per wave
#define GXT   64               // x tiles (64 out cols)
#define GYB   128              // y bands (32 out rows)
#define NB    2048             // (64*128)/4 waves per block

typedef short bf16x8 __attribute__((ext_vector_type(8)));
typedef float f32x4  __attribute__((ext_vector_type(4)));
typedef unsigned short u16;
typedef unsigned int   u32;

__device__ __forceinline__ u16 f2bf(float f) {   // fp32 -> bf16 RNE (finite)
    u32 u = __builtin_bit_cast(u32, f);
    u += 0x7fffu + ((u >> 16) & 1u);
    return (u16)(u >> 16);
}

// Wave-autonomous MFMA conv: wave owns 64x32 outputs (2 stripes x 4 col-tiles
// of 16x16), barrier-free. Window 38x80 bf16 reg-staged into XOR-swizzled LDS;
// 7 Toeplitz-band MFMAs per tile (R12-verified fragment layouts).
// Linear dispatch: consecutive waves x-adjacent -> coherent write front.
__global__ __launch_bounds__(256, 4)
void conv7x7_mfma_wave(const float* __restrict__ x,
                       const float* __restrict__ w,
                       const float* __restrict__ bias,
                       float* __restrict__ out)
{
    __shared__ unsigned char lds[4 * WLDS];   // 38,912 B -> 4 blocks/CU

    const int tid  = threadIdx.x;
    const int lane = tid & 63;
    const int wv   = tid >> 6;
    unsigned char* wbase = lds + wv * WLDS;

    const int t  = (blockIdx.x << 2) + wv;    // wave-tile id, row-major
    const int bx = t & (GXT - 1);
    const int by = t >> 6;
    const int x0 = bx << 6;                   // 64-col tile base
    const int y0 = by << 5;                   // 32-row band base

    // ---- stage 38 rows x 80 bf16 cols, fp32->bf16, XOR-swizzled writes ----
    // chunk m -> (row = m/20, cc = m%20); 8B chunk at logical off cc*8 goes to
    // phys off (cc*8) ^ ((row&7)<<4)  (bijective within the 256B row).
    #pragma unroll
    for (int k = 0; k < 12; ++k) {
        const int m = (k << 6) + lane;
        if (m < 760) {
            const int row = m / 20;                       // magic-mul
            const int cc  = m - row * 20;
            const int gy  = min(y0 + row, N - 1);         // edge clamps: finite
            const int gc  = min(x0 + (cc << 2), N - 4);   // junk, zero-weighted
            const float4 v = *reinterpret_cast<const float4*>(
                x + ((size_t)gy << 12) + gc);
            const u32 lo = (u32)f2bf(v.x) | ((u32)f2bf(v.y) << 16);
            const u32 hi = (u32)f2bf(v.z) | ((u32)f2bf(v.w) << 16);
            const int off = (cc << 3) ^ ((row & 7) << 4);
            u32* dst = reinterpret_cast<u32*>(wbase + row * PITCH + off);
            dst[0] = lo; dst[1] = hi;                     // ds_write_b64
        }
    }

    // ---- build 7 Toeplitz B-fragments from w (L1-resident gathers) ----
    // B[k][n] = w[ky][k-n] for 0<=k-n<7 else 0; k = 8*hq+j, n = nn.
    const int nn = lane & 15;
    const int hq = lane >> 4;
    const int dbase = (hq << 3) - nn;
    bf16x8 bfrag[7];
    #pragma unroll
    for (int ky = 0; ky < 7; ++ky) {
        bf16x8 bb;
        #pragma unroll
        for (int j = 0; j < 8; ++j) {
            const int d  = dbase + j;
            const int wi = ky * 7 + min(max(d, 0), 6);    // in-bounds always
            bb[j] = (d >= 0 && d < 7) ? (short)f2bf(w[wi]) : (short)0;
        }
        bfrag[ky] = bb;
    }
    const float bv = bias[0];

    // all LDS writes drained before fragment reads (same-wave RAW)
    asm volatile("s_waitcnt lgkmcnt(0)" ::: "memory");
    __builtin_amdgcn_sched_barrier(0);

    // ---- MFMA: 2 stripes x 4 col-tiles, 7 Toeplitz MFMAs each ----
    // A[m][k]: window row = st*16 + ky + m (m=nn), col = tc + 8*hq + j.
    f32x4 acc[2][4] = {};
    #pragma unroll
    for (int ky = 0; ky < 7; ++ky) {
        #pragma unroll
        for (int st = 0; st < 2; ++st) {
            const int arow = (st << 4) + ky + nn;          // <= 37
            const unsigned char* rb = wbase + arow * PITCH;
            const int flip = (arow & 7) << 4;
            #pragma unroll
            for (int c = 0; c < 4; ++c) {
                const int off = ((c << 5) + (hq << 4)) ^ flip;  // 16B-aligned
                const bf16x8 af = *reinterpret_cast<const bf16x8*>(rb + off);
                acc[st][c] = __builtin_amdgcn_mfma_f32_16x16x32_bf16(
                    af, bfrag[ky], acc[st][c], 0, 0, 0);
            }
        }
    }

    // ---- store: D col = x0+tc+nn, row = y0+st*16+4*hq+r ----
    // each (st,c,r) instr = 16-lane 64B contiguous runs; x-adjacent waves are
    // temporally coherent (linear dispatch) -> partial lines merge in L2/L3.
    const bool interior = (x0 + 64 <= ON) && (y0 + 32 <= ON);
    #pragma unroll
    for (int st = 0; st < 2; ++st) {
        #pragma unroll
        for (int c = 0; c < 4; ++c) {
            const int ox  = x0 + (c << 4) + nn;
            const int oyb = y0 + (st << 4) + (hq << 2);
            #pragma unroll
            for (int r = 0; r < 4; ++r) {
                const int oy = oyb + r;
                if (interior || (oy < ON && ox < ON))
                    out[(size_t)oy * ON + ox] = acc[st][c][r] + bv;
            }
        }
    }
}

extern "C" void kernel_launch(void* const* d_in, const int* in_sizes, int n_in,
                              void* d_out, int out_size, void* d_ws, size_t ws_size,
                              hipStream_t stream) {
    const float* x    = (const float*)d_in[0];
    const float* w    = (const float*)d_in[1];
    const float* bias = (const float*)d_in[2];
    float* out        = (float*)d_out;

    conv7x7_mfma_wave<<<dim3(NB, 1, 1), dim3(256, 1, 1), 0, stream>>>(x, w, bias, out);
}